// Round 3
// baseline (410.980 us; speedup 1.0000x reference)
//
#include <hip/hip_runtime.h>

#define NN 50000
#define NE 800000
#define FIN 512
#define HID 128
#define NOUT 40
#define NB_SCAN 49   // ceil(50000/1024)

typedef __bf16 v8bf __attribute__((ext_vector_type(8)));
typedef float  v4f  __attribute__((ext_vector_type(4)));
typedef unsigned short us8 __attribute__((ext_vector_type(8)));
typedef unsigned short us4 __attribute__((ext_vector_type(4)));

static __device__ __forceinline__ unsigned short f2bf(float f) {
  union { float f; unsigned int u; } v; v.f = f;
  unsigned int r = v.u + 0x7FFFu + ((v.u >> 16) & 1u);
  return (unsigned short)(r >> 16);
}
static __device__ __forceinline__ float bf2f(unsigned short s) {
  union { unsigned int u; float f; } v; v.u = ((unsigned int)s) << 16;
  return v.f;
}
static __device__ __forceinline__ float bf_lo(unsigned int u) {
  union { unsigned int u; float f; } v; v.u = u << 16; return v.f;
}
static __device__ __forceinline__ float bf_hi(unsigned int u) {
  union { unsigned int u; float f; } v; v.u = u & 0xFFFF0000u; return v.f;
}

// ---------- W1 [FIN][HID] f32 -> W1t [HID][FIN] bf16 ; also zero counts ----------
__global__ void k_w1t(const float* __restrict__ W1, unsigned short* __restrict__ W1t,
                      int* __restrict__ counts) {
  int id = blockIdx.x * 256 + threadIdx.x;   // 65536 threads
  int k = id >> 7;
  int n = id & 127;
  W1t[n * FIN + k] = f2bf(W1[k * HID + n]);
  if (id < NN) counts[id] = 0;
}

// ---------- GEMM1: hb0[NN][HID] = bf16(x @ W1)  (bf16 MFMA, fp32 acc) ----------
#define BM1 64
#define BK1 64
#define BKP1 72
__global__ __launch_bounds__(256) void k_gemm1(const float* __restrict__ x,
                                               const unsigned short* __restrict__ W1t,
                                               unsigned short* __restrict__ hb0) {
  __shared__ unsigned short As[BM1 * BKP1];
  __shared__ unsigned short Bs[HID * BKP1];
  const int t = threadIdx.x;
  const int r0 = blockIdx.x * BM1;
  const int wave = t >> 6, lane = t & 63;
  const int quad = lane >> 4, mr = lane & 15;
  const int mrow0 = (wave & 1) * 32;
  const int ncol0 = (wave >> 1) * 64;

  const int ar = t >> 2, aq = t & 3;
  int grow = r0 + ar; if (grow > NN - 1) grow = NN - 1;
  const float4* xrow = (const float4*)(x + (size_t)grow * FIN);
  const int bn = t >> 1, bh = t & 1;

  const v4f vzero = {0.f, 0.f, 0.f, 0.f};
  v4f acc[2][4];
  #pragma unroll
  for (int mi = 0; mi < 2; ++mi)
    #pragma unroll
    for (int j = 0; j < 4; ++j) acc[mi][j] = vzero;

  for (int k0 = 0; k0 < FIN; k0 += BK1) {
    float4 va[4];
    #pragma unroll
    for (int i = 0; i < 4; ++i) va[i] = xrow[(k0 >> 2) + aq + i * 4];
    us8 vb[4];
    const us8* bp = (const us8*)(W1t + bn * FIN + k0 + bh * 32);
    #pragma unroll
    for (int i = 0; i < 4; ++i) vb[i] = bp[i];

    __syncthreads();
    #pragma unroll
    for (int i = 0; i < 4; ++i) {
      us4 s; s.x = f2bf(va[i].x); s.y = f2bf(va[i].y);
             s.z = f2bf(va[i].z); s.w = f2bf(va[i].w);
      *(us4*)&As[ar * BKP1 + aq * 4 + i * 16] = s;
    }
    #pragma unroll
    for (int i = 0; i < 4; ++i)
      *(us8*)&Bs[bn * BKP1 + bh * 32 + i * 8] = vb[i];
    __syncthreads();

    #pragma unroll
    for (int ks = 0; ks < BK1; ks += 32) {
      v8bf a0 = *(const v8bf*)&As[(mrow0 + mr) * BKP1 + ks + quad * 8];
      v8bf a1 = *(const v8bf*)&As[(mrow0 + 16 + mr) * BKP1 + ks + quad * 8];
      #pragma unroll
      for (int j = 0; j < 4; ++j) {
        v8bf b = *(const v8bf*)&Bs[(ncol0 + j * 16 + mr) * BKP1 + ks + quad * 8];
        acc[0][j] = __builtin_amdgcn_mfma_f32_16x16x32_bf16(a0, b, acc[0][j], 0, 0, 0);
        acc[1][j] = __builtin_amdgcn_mfma_f32_16x16x32_bf16(a1, b, acc[1][j], 0, 0, 0);
      }
    }
  }

  #pragma unroll
  for (int mi = 0; mi < 2; ++mi)
    #pragma unroll
    for (int j = 0; j < 4; ++j)
      #pragma unroll
      for (int rr = 0; rr < 4; ++rr) {
        int row = r0 + mrow0 + mi * 16 + quad * 4 + rr;
        int col = ncol0 + j * 16 + mr;
        if (row < NN) hb0[(size_t)row * HID + col] = f2bf(acc[mi][j][rr]);
      }
}

// ---------- CSR build ----------
__global__ void k_count(const int* __restrict__ dst, int* __restrict__ counts) {
  int e = blockIdx.x * 256 + threadIdx.x;
  if (e < NE) atomicAdd(&counts[dst[e]], 1);
}

__global__ __launch_bounds__(256) void k_scan_local(const int* __restrict__ counts,
                                                    int* __restrict__ tmp,
                                                    int* __restrict__ bsums) {
  __shared__ int wsum[4];
  const int t = threadIdx.x, lane = t & 63, wid = t >> 6;
  const int base = blockIdx.x * 1024 + t * 4;
  int v[4];
  #pragma unroll
  for (int j = 0; j < 4; ++j) {
    int idx = base + j;
    v[j] = (idx < NN) ? counts[idx] : 0;
  }
  int s = v[0] + v[1] + v[2] + v[3];
  int inc = s;
  #pragma unroll
  for (int off = 1; off < 64; off <<= 1) {
    int u = __shfl_up(inc, off);
    if (lane >= off) inc += u;
  }
  if (lane == 63) wsum[wid] = inc;
  __syncthreads();
  if (t == 0) {
    int a = 0;
    #pragma unroll
    for (int j = 0; j < 4; ++j) { int xv = wsum[j]; wsum[j] = a; a += xv; }
    bsums[blockIdx.x] = a;
  }
  __syncthreads();
  int run = (inc - s) + wsum[wid];
  #pragma unroll
  for (int j = 0; j < 4; ++j) {
    int idx = base + j;
    if (idx < NN) tmp[idx] = run;
    run += v[j];
  }
}

__global__ void k_scan_top(int* __restrict__ bsums, int* __restrict__ rowptr) {
  const int lane = threadIdx.x;   // 64 threads
  int v = (lane < NB_SCAN) ? bsums[lane] : 0;
  int inc = v;
  #pragma unroll
  for (int off = 1; off < 64; off <<= 1) {
    int u = __shfl_up(inc, off);
    if (lane >= off) inc += u;
  }
  if (lane < NB_SCAN) bsums[lane] = inc - v;
  if (lane == 63) rowptr[NN] = inc;
}

__global__ __launch_bounds__(256) void k_scan_add(const int* __restrict__ tmp,
                                                  const int* __restrict__ bsums,
                                                  int* __restrict__ rowptr,
                                                  int* __restrict__ nxt) {
  const int t = threadIdx.x;
  const int base = blockIdx.x * 1024 + t * 4;
  const int off = bsums[blockIdx.x];
  #pragma unroll
  for (int j = 0; j < 4; ++j) {
    int idx = base + j;
    if (idx < NN) {
      int val = tmp[idx] + off;
      rowptr[idx] = val;
      nxt[idx] = val;
    }
  }
}

// packed CSR entry: low 32 = src index, high 32 = weight bits
__global__ void k_scatter(const int* __restrict__ src, const int* __restrict__ dst,
                          const float* __restrict__ w, int* __restrict__ nxt,
                          long long* __restrict__ csrp) {
  int e = blockIdx.x * 256 + threadIdx.x;
  if (e < NE) {
    int i = dst[e];
    int p = atomicAdd(&nxt[i], 1);
    long long pk = (long long)(unsigned int)src[e] |
                   ((long long)(unsigned int)__float_as_uint(w[e]) << 32);
    csrp[p] = pk;
  }
}

// ---------- SpMM1 (bf16 gather) + bias + relu + dropout + fused GEMM2 -> h2b bf16 ----
// one wave per row; gather phase: lane covers cols [2*lane, 2*lane+1]
// epilogue: h1 row -> LDS, lanes 0..39 compute h2[c] = dot(h1, W2[:,c]) in fp32
__global__ __launch_bounds__(256) void k_spmm1(const unsigned short* __restrict__ hb0,
                                               const int* __restrict__ rowptr,
                                               const long long* __restrict__ csrp,
                                               const float* __restrict__ b1,
                                               const float* __restrict__ mask,
                                               const float* __restrict__ W2,
                                               unsigned short* __restrict__ h2b) {
  __shared__ float h1s[4][HID];
  const int t = threadIdx.x, lane = t & 63, wv = t >> 6;
  const int i = blockIdx.x * 4 + wv;
  const int c0 = lane * 2;
  const int e0 = rowptr[i], e1 = rowptr[i + 1];
  float a00 = 0.f, a01 = 0.f, a10 = 0.f, a11 = 0.f;
  float a20 = 0.f, a21 = 0.f, a30 = 0.f, a31 = 0.f;
  int e = e0;
  for (; e + 3 < e1; e += 4) {
    long long p0 = csrp[e], p1 = csrp[e + 1], p2 = csrp[e + 2], p3 = csrp[e + 3];
    int s0 = (int)p0, s1 = (int)p1, s2 = (int)p2, s3 = (int)p3;
    float w0 = __uint_as_float((unsigned int)((unsigned long long)p0 >> 32));
    float w1 = __uint_as_float((unsigned int)((unsigned long long)p1 >> 32));
    float w2 = __uint_as_float((unsigned int)((unsigned long long)p2 >> 32));
    float w3 = __uint_as_float((unsigned int)((unsigned long long)p3 >> 32));
    unsigned int u0 = *(const unsigned int*)&hb0[s0 * HID + c0];
    unsigned int u1 = *(const unsigned int*)&hb0[s1 * HID + c0];
    unsigned int u2 = *(const unsigned int*)&hb0[s2 * HID + c0];
    unsigned int u3 = *(const unsigned int*)&hb0[s3 * HID + c0];
    a00 += w0 * bf_lo(u0); a01 += w0 * bf_hi(u0);
    a10 += w1 * bf_lo(u1); a11 += w1 * bf_hi(u1);
    a20 += w2 * bf_lo(u2); a21 += w2 * bf_hi(u2);
    a30 += w3 * bf_lo(u3); a31 += w3 * bf_hi(u3);
  }
  for (; e < e1; ++e) {
    long long p = csrp[e];
    int s = (int)p;
    float w = __uint_as_float((unsigned int)((unsigned long long)p >> 32));
    unsigned int u = *(const unsigned int*)&hb0[s * HID + c0];
    a00 += w * bf_lo(u); a01 += w * bf_hi(u);
  }
  const float2 bb = *(const float2*)&b1[c0];
  const float2 mk = *(const float2*)&mask[(size_t)i * HID + c0];
  float v0 = (a00 + a10) + (a20 + a30) + bb.x;
  float v1 = (a01 + a11) + (a21 + a31) + bb.y;
  v0 = fmaxf(v0, 0.f) * mk.x;
  v1 = fmaxf(v1, 0.f) * mk.y;
  h1s[wv][c0] = v0;
  h1s[wv][c0 + 1] = v1;
  __syncthreads();   // all 256 threads reach exactly once; orders LDS writes

  // fused GEMM2: h2[i][c] = dot(h1 row, W2[:,c]); W2 fp32, L1-resident (20 KB)
  if (lane < NOUT) {
    const int c = lane;
    float acc0 = 0.f, acc1 = 0.f, acc2 = 0.f, acc3 = 0.f;
    #pragma unroll 4
    for (int k = 0; k < HID; k += 4) {
      float4 hv = *(const float4*)&h1s[wv][k];   // broadcast ds_read_b128
      acc0 += hv.x * W2[(k    ) * NOUT + c];
      acc1 += hv.y * W2[(k + 1) * NOUT + c];
      acc2 += hv.z * W2[(k + 2) * NOUT + c];
      acc3 += hv.w * W2[(k + 3) * NOUT + c];
    }
    h2b[(size_t)i * NOUT + c] = f2bf((acc0 + acc1) + (acc2 + acc3));
  }
}

// ---------- SpMM2 (bf16 gather) + b2 -> out fp32 ----------
__global__ __launch_bounds__(256) void k_spmm2(const unsigned short* __restrict__ h2b,
                                               const int* __restrict__ rowptr,
                                               const long long* __restrict__ csrp,
                                               const float* __restrict__ b2,
                                               float* __restrict__ out) {
  const int t = threadIdx.x;
  const int lane = t & 63;
  const int i = blockIdx.x * 4 + (t >> 6);
  if (i >= NN) return;
  const int e0 = rowptr[i], e1 = rowptr[i + 1];
  if (lane >= NOUT) return;
  float a0 = 0.f, a1 = 0.f, a2 = 0.f, a3 = 0.f;
  int e = e0;
  for (; e + 3 < e1; e += 4) {
    long long p0 = csrp[e], p1 = csrp[e + 1], p2 = csrp[e + 2], p3 = csrp[e + 3];
    int s0 = (int)p0, s1 = (int)p1, s2 = (int)p2, s3 = (int)p3;
    float w0 = __uint_as_float((unsigned int)((unsigned long long)p0 >> 32));
    float w1 = __uint_as_float((unsigned int)((unsigned long long)p1 >> 32));
    float w2 = __uint_as_float((unsigned int)((unsigned long long)p2 >> 32));
    float w3 = __uint_as_float((unsigned int)((unsigned long long)p3 >> 32));
    a0 += w0 * bf2f(h2b[s0 * NOUT + lane]);
    a1 += w1 * bf2f(h2b[s1 * NOUT + lane]);
    a2 += w2 * bf2f(h2b[s2 * NOUT + lane]);
    a3 += w3 * bf2f(h2b[s3 * NOUT + lane]);
  }
  for (; e < e1; ++e) {
    long long p = csrp[e];
    int s = (int)p;
    float w = __uint_as_float((unsigned int)((unsigned long long)p >> 32));
    a0 += w * bf2f(h2b[s * NOUT + lane]);
  }
  out[(size_t)i * NOUT + lane] = (a0 + a1) + (a2 + a3) + b2[lane];
}

extern "C" void kernel_launch(void* const* d_in, const int* in_sizes, int n_in,
                              void* d_out, int out_size, void* d_ws, size_t ws_size,
                              hipStream_t stream) {
  const float* x   = (const float*)d_in[0];
  const float* W1  = (const float*)d_in[1];
  const float* b1  = (const float*)d_in[2];
  const float* W2  = (const float*)d_in[3];
  const float* b2  = (const float*)d_in[4];
  const float* ew  = (const float*)d_in[5];
  const float* msk = (const float*)d_in[6];
  const int* esrc  = (const int*)d_in[7];
  const int* edst  = (const int*)d_in[8];
  float* out = (float*)d_out;

  char* ws = (char*)d_ws;
  unsigned short* hb0 = (unsigned short*)ws; ws += (size_t)NN * HID * 2;   // 12.8 MB
  unsigned short* h2b = (unsigned short*)ws; ws += (size_t)NN * NOUT * 2;  // 4 MB
  unsigned short* W1t = (unsigned short*)ws; ws += (size_t)HID * FIN * 2;  // 128 KB
  long long* csrp     = (long long*)ws;      ws += (size_t)NE * 8;         // 6.4 MB
  int* counts         = (int*)ws;            ws += (size_t)NN * 4;
  int* tmp            = (int*)ws;            ws += (size_t)NN * 4;
  int* rowptr         = (int*)ws;            ws += (size_t)(NN + 16) * 4;
  int* nxt            = (int*)ws;            ws += (size_t)NN * 4;
  int* bsums          = (int*)ws;            ws += (size_t)64 * 4;

  k_w1t       <<<(FIN * HID) / 256, 256, 0, stream>>>(W1, W1t, counts);
  k_gemm1     <<<(NN + BM1 - 1) / BM1, 256, 0, stream>>>(x, W1t, hb0);
  k_count     <<<(NE + 255) / 256, 256, 0, stream>>>(edst, counts);
  k_scan_local<<<NB_SCAN, 256, 0, stream>>>(counts, tmp, bsums);
  k_scan_top  <<<1, 64, 0, stream>>>(bsums, rowptr);
  k_scan_add  <<<NB_SCAN, 256, 0, stream>>>(tmp, bsums, rowptr, nxt);
  k_scatter   <<<(NE + 255) / 256, 256, 0, stream>>>(esrc, edst, ew, nxt, csrp);
  k_spmm1     <<<NN / 4, 256, 0, stream>>>(hb0, rowptr, csrp, b1, msk, W2, h2b);
  k_spmm2     <<<(NN + 3) / 4, 256, 0, stream>>>(h2b, rowptr, csrp, b2, out);
}

// Round 4
// 375.010 us; speedup vs baseline: 1.0959x; 1.0959x over previous
//
#include <hip/hip_runtime.h>

#define NN 50000
#define NE 800000
#define FIN 512
#define HID 128
#define NOUT 40
#define NB_SCAN 49   // ceil(50000/1024)

typedef __bf16 v8bf __attribute__((ext_vector_type(8)));
typedef float  v4f  __attribute__((ext_vector_type(4)));
typedef unsigned short us8 __attribute__((ext_vector_type(8)));
typedef unsigned short us4 __attribute__((ext_vector_type(4)));

static __device__ __forceinline__ unsigned short f2bf(float f) {
  union { float f; unsigned int u; } v; v.f = f;
  unsigned int r = v.u + 0x7FFFu + ((v.u >> 16) & 1u);
  return (unsigned short)(r >> 16);
}
static __device__ __forceinline__ float bf2f(unsigned short s) {
  union { unsigned int u; float f; } v; v.u = ((unsigned int)s) << 16;
  return v.f;
}

// ---------- W1 [FIN][HID] f32 -> W1t [HID][FIN] bf16 ; also zero counts ----------
__global__ void k_w1t(const float* __restrict__ W1, unsigned short* __restrict__ W1t,
                      int* __restrict__ counts) {
  int id = blockIdx.x * 256 + threadIdx.x;   // 65536 threads
  int k = id >> 7;
  int n = id & 127;
  W1t[n * FIN + k] = f2bf(W1[k * HID + n]);
  if (id < NN) counts[id] = 0;
}

// ---------- GEMM1: hb0[NN][HID] = bf16(x @ W1)  (bf16 MFMA, fp32 acc) ----------
#define BM1 64
#define BK1 64
#define BKP1 72
__global__ __launch_bounds__(256) void k_gemm1(const float* __restrict__ x,
                                               const unsigned short* __restrict__ W1t,
                                               unsigned short* __restrict__ hb0) {
  __shared__ unsigned short As[BM1 * BKP1];
  __shared__ unsigned short Bs[HID * BKP1];
  const int t = threadIdx.x;
  const int r0 = blockIdx.x * BM1;
  const int wave = t >> 6, lane = t & 63;
  const int quad = lane >> 4, mr = lane & 15;
  const int mrow0 = (wave & 1) * 32;
  const int ncol0 = (wave >> 1) * 64;

  const int ar = t >> 2, aq = t & 3;
  int grow = r0 + ar; if (grow > NN - 1) grow = NN - 1;
  const float4* xrow = (const float4*)(x + (size_t)grow * FIN);
  const int bn = t >> 1, bh = t & 1;

  const v4f vzero = {0.f, 0.f, 0.f, 0.f};
  v4f acc[2][4];
  #pragma unroll
  for (int mi = 0; mi < 2; ++mi)
    #pragma unroll
    for (int j = 0; j < 4; ++j) acc[mi][j] = vzero;

  for (int k0 = 0; k0 < FIN; k0 += BK1) {
    float4 va[4];
    #pragma unroll
    for (int i = 0; i < 4; ++i) va[i] = xrow[(k0 >> 2) + aq + i * 4];
    us8 vb[4];
    const us8* bp = (const us8*)(W1t + bn * FIN + k0 + bh * 32);
    #pragma unroll
    for (int i = 0; i < 4; ++i) vb[i] = bp[i];

    __syncthreads();
    #pragma unroll
    for (int i = 0; i < 4; ++i) {
      us4 s; s.x = f2bf(va[i].x); s.y = f2bf(va[i].y);
             s.z = f2bf(va[i].z); s.w = f2bf(va[i].w);
      *(us4*)&As[ar * BKP1 + aq * 4 + i * 16] = s;
    }
    #pragma unroll
    for (int i = 0; i < 4; ++i)
      *(us8*)&Bs[bn * BKP1 + bh * 32 + i * 8] = vb[i];
    __syncthreads();

    #pragma unroll
    for (int ks = 0; ks < BK1; ks += 32) {
      v8bf a0 = *(const v8bf*)&As[(mrow0 + mr) * BKP1 + ks + quad * 8];
      v8bf a1 = *(const v8bf*)&As[(mrow0 + 16 + mr) * BKP1 + ks + quad * 8];
      #pragma unroll
      for (int j = 0; j < 4; ++j) {
        v8bf b = *(const v8bf*)&Bs[(ncol0 + j * 16 + mr) * BKP1 + ks + quad * 8];
        acc[0][j] = __builtin_amdgcn_mfma_f32_16x16x32_bf16(a0, b, acc[0][j], 0, 0, 0);
        acc[1][j] = __builtin_amdgcn_mfma_f32_16x16x32_bf16(a1, b, acc[1][j], 0, 0, 0);
      }
    }
  }

  #pragma unroll
  for (int mi = 0; mi < 2; ++mi)
    #pragma unroll
    for (int j = 0; j < 4; ++j)
      #pragma unroll
      for (int rr = 0; rr < 4; ++rr) {
        int row = r0 + mrow0 + mi * 16 + quad * 4 + rr;
        int col = ncol0 + j * 16 + mr;
        if (row < NN) hb0[(size_t)row * HID + col] = f2bf(acc[mi][j][rr]);
      }
}

// ---------- CSR build ----------
__global__ void k_count(const int* __restrict__ dst, int* __restrict__ counts) {
  int e = blockIdx.x * 256 + threadIdx.x;
  if (e < NE) atomicAdd(&counts[dst[e]], 1);
}

__global__ __launch_bounds__(256) void k_scan_local(const int* __restrict__ counts,
                                                    int* __restrict__ tmp,
                                                    int* __restrict__ bsums) {
  __shared__ int wsum[4];
  const int t = threadIdx.x, lane = t & 63, wid = t >> 6;
  const int base = blockIdx.x * 1024 + t * 4;
  int v[4];
  #pragma unroll
  for (int j = 0; j < 4; ++j) {
    int idx = base + j;
    v[j] = (idx < NN) ? counts[idx] : 0;
  }
  int s = v[0] + v[1] + v[2] + v[3];
  int inc = s;
  #pragma unroll
  for (int off = 1; off < 64; off <<= 1) {
    int u = __shfl_up(inc, off);
    if (lane >= off) inc += u;
  }
  if (lane == 63) wsum[wid] = inc;
  __syncthreads();
  if (t == 0) {
    int a = 0;
    #pragma unroll
    for (int j = 0; j < 4; ++j) { int xv = wsum[j]; wsum[j] = a; a += xv; }
    bsums[blockIdx.x] = a;
  }
  __syncthreads();
  int run = (inc - s) + wsum[wid];
  #pragma unroll
  for (int j = 0; j < 4; ++j) {
    int idx = base + j;
    if (idx < NN) tmp[idx] = run;
    run += v[j];
  }
}

__global__ void k_scan_top(int* __restrict__ bsums, int* __restrict__ rowptr) {
  const int lane = threadIdx.x;   // 64 threads
  int v = (lane < NB_SCAN) ? bsums[lane] : 0;
  int inc = v;
  #pragma unroll
  for (int off = 1; off < 64; off <<= 1) {
    int u = __shfl_up(inc, off);
    if (lane >= off) inc += u;
  }
  if (lane < NB_SCAN) bsums[lane] = inc - v;
  if (lane == 63) rowptr[NN] = inc;
}

__global__ __launch_bounds__(256) void k_scan_add(const int* __restrict__ tmp,
                                                  const int* __restrict__ bsums,
                                                  int* __restrict__ rowptr,
                                                  int* __restrict__ nxt) {
  const int t = threadIdx.x;
  const int base = blockIdx.x * 1024 + t * 4;
  const int off = bsums[blockIdx.x];
  #pragma unroll
  for (int j = 0; j < 4; ++j) {
    int idx = base + j;
    if (idx < NN) {
      int val = tmp[idx] + off;
      rowptr[idx] = val;
      nxt[idx] = val;
    }
  }
}

// packed CSR entry: low 32 = src index, high 32 = weight bits
__global__ void k_scatter(const int* __restrict__ src, const int* __restrict__ dst,
                          const float* __restrict__ w, int* __restrict__ nxt,
                          long long* __restrict__ csrp) {
  int e = blockIdx.x * 256 + threadIdx.x;
  if (e < NE) {
    int i = dst[e];
    int p = atomicAdd(&nxt[i], 1);
    long long pk = (long long)(unsigned int)src[e] |
                   ((long long)(unsigned int)__float_as_uint(w[e]) << 32);
    csrp[p] = pk;
  }
}

// ---------- SpMM1: half-wave per edge, 2 edges/wave concurrent ----------
// lane = side*32 + hl; lane covers cols [4*hl, 4*hl+4) via ushort4 (8B) loads.
// side 0 takes edges e0, e0+2, ...; side 1 takes e0+1, e0+3, ...
// partials combined via __shfl_xor(32); lanes 0..31 write the bf16 row.
__global__ __launch_bounds__(256) void k_spmm1(const unsigned short* __restrict__ hb0,
                                               const int* __restrict__ rowptr,
                                               const long long* __restrict__ csrp,
                                               const float* __restrict__ b1,
                                               const float* __restrict__ mask,
                                               unsigned short* __restrict__ hb1) {
  const int t = threadIdx.x, lane = t & 63, wv = t >> 6;
  const int side = lane >> 5, hl = lane & 31;
  const int i = blockIdx.x * 4 + wv;
  const int c0 = hl * 4;
  const int e0 = rowptr[i], e1 = rowptr[i + 1];
  const int nE = e1 - e0;
  const int m = (nE + 1 - side) >> 1;          // edges handled by this side
  const long long* ep = csrp + e0 + side;

  float ax[4] = {0.f, 0.f, 0.f, 0.f};
  float ay[4] = {0.f, 0.f, 0.f, 0.f};
  float az[4] = {0.f, 0.f, 0.f, 0.f};
  float aw[4] = {0.f, 0.f, 0.f, 0.f};
  int j = 0;
  for (; j + 3 < m; j += 4) {                  // 8 gathers in flight per wave
    long long p0 = ep[2*j], p1 = ep[2*j+2], p2 = ep[2*j+4], p3 = ep[2*j+6];
    int s0 = (int)p0, s1 = (int)p1, s2 = (int)p2, s3 = (int)p3;
    float w0 = __uint_as_float((unsigned int)((unsigned long long)p0 >> 32));
    float w1 = __uint_as_float((unsigned int)((unsigned long long)p1 >> 32));
    float w2 = __uint_as_float((unsigned int)((unsigned long long)p2 >> 32));
    float w3 = __uint_as_float((unsigned int)((unsigned long long)p3 >> 32));
    us4 h0 = *(const us4*)&hb0[s0 * HID + c0];
    us4 h1 = *(const us4*)&hb0[s1 * HID + c0];
    us4 h2 = *(const us4*)&hb0[s2 * HID + c0];
    us4 h3 = *(const us4*)&hb0[s3 * HID + c0];
    ax[0] += w0 * bf2f(h0.x); ay[0] += w0 * bf2f(h0.y); az[0] += w0 * bf2f(h0.z); aw[0] += w0 * bf2f(h0.w);
    ax[1] += w1 * bf2f(h1.x); ay[1] += w1 * bf2f(h1.y); az[1] += w1 * bf2f(h1.z); aw[1] += w1 * bf2f(h1.w);
    ax[2] += w2 * bf2f(h2.x); ay[2] += w2 * bf2f(h2.y); az[2] += w2 * bf2f(h2.z); aw[2] += w2 * bf2f(h2.w);
    ax[3] += w3 * bf2f(h3.x); ay[3] += w3 * bf2f(h3.y); az[3] += w3 * bf2f(h3.z); aw[3] += w3 * bf2f(h3.w);
  }
  for (; j < m; ++j) {
    long long p = ep[2*j];
    int s = (int)p;
    float w = __uint_as_float((unsigned int)((unsigned long long)p >> 32));
    us4 h = *(const us4*)&hb0[s * HID + c0];
    ax[0] += w * bf2f(h.x); ay[0] += w * bf2f(h.y);
    az[0] += w * bf2f(h.z); aw[0] += w * bf2f(h.w);
  }
  float vx = (ax[0] + ax[1]) + (ax[2] + ax[3]);
  float vy = (ay[0] + ay[1]) + (ay[2] + ay[3]);
  float vz = (az[0] + az[1]) + (az[2] + az[3]);
  float vw = (aw[0] + aw[1]) + (aw[2] + aw[3]);
  vx += __shfl_xor(vx, 32);
  vy += __shfl_xor(vy, 32);
  vz += __shfl_xor(vz, 32);
  vw += __shfl_xor(vw, 32);
  if (side == 0) {
    const float4 bb = *(const float4*)&b1[c0];
    const float4 mk = *(const float4*)&mask[(size_t)i * HID + c0];
    vx = fmaxf(vx + bb.x, 0.f) * mk.x;
    vy = fmaxf(vy + bb.y, 0.f) * mk.y;
    vz = fmaxf(vz + bb.z, 0.f) * mk.z;
    vw = fmaxf(vw + bb.w, 0.f) * mk.w;
    us4 o; o.x = f2bf(vx); o.y = f2bf(vy); o.z = f2bf(vz); o.w = f2bf(vw);
    *(us4*)&hb1[(size_t)i * HID + c0] = o;
  }
}

// ---------- GEMM2: h2b[NN][40] = bf16(hb1 @ W2) (bf16 MFMA, 48-col padded) ----------
#define BKP2 136
__global__ __launch_bounds__(256) void k_gemm2(const unsigned short* __restrict__ hb1,
                                               const float* __restrict__ W2,
                                               unsigned short* __restrict__ h2b) {
  __shared__ unsigned short As[64 * BKP2];
  __shared__ unsigned short Bs[48 * BKP2];
  const int t = threadIdx.x;
  const int r0 = blockIdx.x * 64;
  const int wave = t >> 6, lane = t & 63;
  const int quad = lane >> 4, mr = lane & 15;
  const int mrow0 = wave * 16;

  const int ar = t >> 2, aq = t & 3;
  int grow = r0 + ar; if (grow > NN - 1) grow = NN - 1;
  const us8* hrow = (const us8*)(hb1 + (size_t)grow * HID);
  #pragma unroll
  for (int i = 0; i < 4; ++i) {
    us8 v = hrow[aq + i * 4];
    *(us8*)&As[ar * BKP2 + aq * 8 + i * 32] = v;
  }
  if (t < 192) {
    int n = t >> 2, q = t & 3;
    #pragma unroll
    for (int kk = 0; kk < 32; ++kk) {
      int k = q * 32 + kk;
      float val = (n < NOUT) ? W2[k * NOUT + n] : 0.f;
      Bs[n * BKP2 + k] = f2bf(val);
    }
  }
  __syncthreads();

  const v4f vzero = {0.f, 0.f, 0.f, 0.f};
  v4f acc[3] = {vzero, vzero, vzero};
  #pragma unroll
  for (int ks = 0; ks < HID; ks += 32) {
    v8bf a = *(const v8bf*)&As[(mrow0 + mr) * BKP2 + ks + quad * 8];
    #pragma unroll
    for (int j = 0; j < 3; ++j) {
      v8bf b = *(const v8bf*)&Bs[(j * 16 + mr) * BKP2 + ks + quad * 8];
      acc[j] = __builtin_amdgcn_mfma_f32_16x16x32_bf16(a, b, acc[j], 0, 0, 0);
    }
  }
  #pragma unroll
  for (int j = 0; j < 3; ++j)
    #pragma unroll
    for (int rr = 0; rr < 4; ++rr) {
      int row = r0 + mrow0 + quad * 4 + rr;
      int col = j * 16 + mr;
      if (row < NN && col < NOUT) h2b[(size_t)row * NOUT + col] = f2bf(acc[j][rr]);
    }
}

// ---------- SpMM2: 20-lane groups, 2 edges/wave concurrent ----------
// lane = side*32 + q, active if q<20; covers cols [2q, 2q+1] via ushort2 (4B).
__global__ __launch_bounds__(256) void k_spmm2(const unsigned short* __restrict__ h2b,
                                               const int* __restrict__ rowptr,
                                               const long long* __restrict__ csrp,
                                               const float* __restrict__ b2,
                                               float* __restrict__ out) {
  const int t = threadIdx.x, lane = t & 63;
  const int side = lane >> 5, q = lane & 31;
  const int i = blockIdx.x * 4 + (t >> 6);
  const int act = (q < 20);
  const int c0 = act ? q * 2 : 0;              // clamp inactive lanes in-bounds
  const int e0 = rowptr[i], e1 = rowptr[i + 1];
  const int nE = e1 - e0;
  const int m = (nE + 1 - side) >> 1;
  const long long* ep = csrp + e0 + side;

  float a0[4] = {0.f, 0.f, 0.f, 0.f};
  float a1[4] = {0.f, 0.f, 0.f, 0.f};
  int j = 0;
  for (; j + 3 < m; j += 4) {
    long long p0 = ep[2*j], p1 = ep[2*j+2], p2 = ep[2*j+4], p3 = ep[2*j+6];
    int s0 = (int)p0, s1 = (int)p1, s2 = (int)p2, s3 = (int)p3;
    float w0 = __uint_as_float((unsigned int)((unsigned long long)p0 >> 32));
    float w1 = __uint_as_float((unsigned int)((unsigned long long)p1 >> 32));
    float w2 = __uint_as_float((unsigned int)((unsigned long long)p2 >> 32));
    float w3 = __uint_as_float((unsigned int)((unsigned long long)p3 >> 32));
    unsigned int u0 = *(const unsigned int*)&h2b[s0 * NOUT + c0];
    unsigned int u1 = *(const unsigned int*)&h2b[s1 * NOUT + c0];
    unsigned int u2 = *(const unsigned int*)&h2b[s2 * NOUT + c0];
    unsigned int u3 = *(const unsigned int*)&h2b[s3 * NOUT + c0];
    a0[0] += w0 * bf2f((unsigned short)u0); a1[0] += w0 * bf2f((unsigned short)(u0 >> 16));
    a0[1] += w1 * bf2f((unsigned short)u1); a1[1] += w1 * bf2f((unsigned short)(u1 >> 16));
    a0[2] += w2 * bf2f((unsigned short)u2); a1[2] += w2 * bf2f((unsigned short)(u2 >> 16));
    a0[3] += w3 * bf2f((unsigned short)u3); a1[3] += w3 * bf2f((unsigned short)(u3 >> 16));
  }
  for (; j < m; ++j) {
    long long p = ep[2*j];
    int s = (int)p;
    float w = __uint_as_float((unsigned int)((unsigned long long)p >> 32));
    unsigned int u = *(const unsigned int*)&h2b[s * NOUT + c0];
    a0[0] += w * bf2f((unsigned short)u);
    a1[0] += w * bf2f((unsigned short)(u >> 16));
  }
  float v0 = (a0[0] + a0[1]) + (a0[2] + a0[3]);
  float v1 = (a1[0] + a1[1]) + (a1[2] + a1[3]);
  v0 += __shfl_xor(v0, 32);
  v1 += __shfl_xor(v1, 32);
  if (side == 0 && act) {
    float2 o;
    o.x = v0 + b2[c0];
    o.y = v1 + b2[c0 + 1];
    *(float2*)&out[(size_t)i * NOUT + c0] = o;
  }
}

extern "C" void kernel_launch(void* const* d_in, const int* in_sizes, int n_in,
                              void* d_out, int out_size, void* d_ws, size_t ws_size,
                              hipStream_t stream) {
  const float* x   = (const float*)d_in[0];
  const float* W1  = (const float*)d_in[1];
  const float* b1  = (const float*)d_in[2];
  const float* W2  = (const float*)d_in[3];
  const float* b2  = (const float*)d_in[4];
  const float* ew  = (const float*)d_in[5];
  const float* msk = (const float*)d_in[6];
  const int* esrc  = (const int*)d_in[7];
  const int* edst  = (const int*)d_in[8];
  float* out = (float*)d_out;

  char* ws = (char*)d_ws;
  unsigned short* hb0 = (unsigned short*)ws; ws += (size_t)NN * HID * 2;   // 12.8 MB
  unsigned short* hb1 = (unsigned short*)ws; ws += (size_t)NN * HID * 2;   // 12.8 MB
  unsigned short* h2b = (unsigned short*)ws; ws += (size_t)NN * NOUT * 2;  // 4 MB
  unsigned short* W1t = (unsigned short*)ws; ws += (size_t)HID * FIN * 2;  // 128 KB
  long long* csrp     = (long long*)ws;      ws += (size_t)NE * 8;         // 6.4 MB
  int* counts         = (int*)ws;            ws += (size_t)NN * 4;
  int* tmp            = (int*)ws;            ws += (size_t)NN * 4;
  int* rowptr         = (int*)ws;            ws += (size_t)(NN + 16) * 4;
  int* nxt            = (int*)ws;            ws += (size_t)NN * 4;
  int* bsums          = (int*)ws;            ws += (size_t)64 * 4;

  k_w1t       <<<(FIN * HID) / 256, 256, 0, stream>>>(W1, W1t, counts);
  k_gemm1     <<<(NN + BM1 - 1) / BM1, 256, 0, stream>>>(x, W1t, hb0);
  k_count     <<<(NE + 255) / 256, 256, 0, stream>>>(edst, counts);
  k_scan_local<<<NB_SCAN, 256, 0, stream>>>(counts, tmp, bsums);
  k_scan_top  <<<1, 64, 0, stream>>>(bsums, rowptr);
  k_scan_add  <<<NB_SCAN, 256, 0, stream>>>(tmp, bsums, rowptr, nxt);
  k_scatter   <<<(NE + 255) / 256, 256, 0, stream>>>(esrc, edst, ew, nxt, csrp);
  k_spmm1     <<<NN / 4, 256, 0, stream>>>(hb0, rowptr, csrp, b1, msk, hb1);
  k_gemm2     <<<(NN + 63) / 64, 256, 0, stream>>>(hb1, W2, h2b);
  k_spmm2     <<<(NN + 3) / 4, 256, 0, stream>>>(h2b, rowptr, csrp, b2, out);
}

// Round 5
// 371.254 us; speedup vs baseline: 1.1070x; 1.0101x over previous
//
#include <hip/hip_runtime.h>

#define NN 50000
#define NE 800000
#define FIN 512
#define HID 128
#define NOUT 40
#define NB_SCAN 49   // ceil(50000/1024)

typedef __bf16 v8bf __attribute__((ext_vector_type(8)));
typedef float  v4f  __attribute__((ext_vector_type(4)));
typedef unsigned short us8 __attribute__((ext_vector_type(8)));
typedef unsigned short us4 __attribute__((ext_vector_type(4)));

static __device__ __forceinline__ unsigned short f2bf(float f) {
  union { float f; unsigned int u; } v; v.f = f;
  unsigned int r = v.u + 0x7FFFu + ((v.u >> 16) & 1u);
  return (unsigned short)(r >> 16);
}
static __device__ __forceinline__ float bf2f(unsigned short s) {
  union { unsigned int u; float f; } v; v.u = ((unsigned int)s) << 16;
  return v.f;
}

// ---------- W1 [FIN][HID] f32 -> W1t [HID][FIN] bf16 ; also zero counts ----------
__global__ void k_w1t(const float* __restrict__ W1, unsigned short* __restrict__ W1t,
                      int* __restrict__ counts) {
  int id = blockIdx.x * 256 + threadIdx.x;   // 65536 threads
  int k = id >> 7;
  int n = id & 127;
  W1t[n * FIN + k] = f2bf(W1[k * HID + n]);
  if (id < NN) counts[id] = 0;
}

// ---------- GEMM1: hb0[NN][HID] = bf16(x @ W1)  (bf16 MFMA, fp32 acc) ----------
#define BM1 64
#define BK1 64
#define BKP1 72
__global__ __launch_bounds__(256) void k_gemm1(const float* __restrict__ x,
                                               const unsigned short* __restrict__ W1t,
                                               unsigned short* __restrict__ hb0) {
  __shared__ unsigned short As[BM1 * BKP1];
  __shared__ unsigned short Bs[HID * BKP1];
  const int t = threadIdx.x;
  const int r0 = blockIdx.x * BM1;
  const int wave = t >> 6, lane = t & 63;
  const int quad = lane >> 4, mr = lane & 15;
  const int mrow0 = (wave & 1) * 32;
  const int ncol0 = (wave >> 1) * 64;

  const int ar = t >> 2, aq = t & 3;
  int grow = r0 + ar; if (grow > NN - 1) grow = NN - 1;
  const float4* xrow = (const float4*)(x + (size_t)grow * FIN);
  const int bn = t >> 1, bh = t & 1;

  const v4f vzero = {0.f, 0.f, 0.f, 0.f};
  v4f acc[2][4];
  #pragma unroll
  for (int mi = 0; mi < 2; ++mi)
    #pragma unroll
    for (int j = 0; j < 4; ++j) acc[mi][j] = vzero;

  for (int k0 = 0; k0 < FIN; k0 += BK1) {
    float4 va[4];
    #pragma unroll
    for (int i = 0; i < 4; ++i) va[i] = xrow[(k0 >> 2) + aq + i * 4];
    us8 vb[4];
    const us8* bp = (const us8*)(W1t + bn * FIN + k0 + bh * 32);
    #pragma unroll
    for (int i = 0; i < 4; ++i) vb[i] = bp[i];

    __syncthreads();
    #pragma unroll
    for (int i = 0; i < 4; ++i) {
      us4 s; s.x = f2bf(va[i].x); s.y = f2bf(va[i].y);
             s.z = f2bf(va[i].z); s.w = f2bf(va[i].w);
      *(us4*)&As[ar * BKP1 + aq * 4 + i * 16] = s;
    }
    #pragma unroll
    for (int i = 0; i < 4; ++i)
      *(us8*)&Bs[bn * BKP1 + bh * 32 + i * 8] = vb[i];
    __syncthreads();

    #pragma unroll
    for (int ks = 0; ks < BK1; ks += 32) {
      v8bf a0 = *(const v8bf*)&As[(mrow0 + mr) * BKP1 + ks + quad * 8];
      v8bf a1 = *(const v8bf*)&As[(mrow0 + 16 + mr) * BKP1 + ks + quad * 8];
      #pragma unroll
      for (int j = 0; j < 4; ++j) {
        v8bf b = *(const v8bf*)&Bs[(ncol0 + j * 16 + mr) * BKP1 + ks + quad * 8];
        acc[0][j] = __builtin_amdgcn_mfma_f32_16x16x32_bf16(a0, b, acc[0][j], 0, 0, 0);
        acc[1][j] = __builtin_amdgcn_mfma_f32_16x16x32_bf16(a1, b, acc[1][j], 0, 0, 0);
      }
    }
  }

  #pragma unroll
  for (int mi = 0; mi < 2; ++mi)
    #pragma unroll
    for (int j = 0; j < 4; ++j)
      #pragma unroll
      for (int rr = 0; rr < 4; ++rr) {
        int row = r0 + mrow0 + mi * 16 + quad * 4 + rr;
        int col = ncol0 + j * 16 + mr;
        if (row < NN) hb0[(size_t)row * HID + col] = f2bf(acc[mi][j][rr]);
      }
}

// ---------- CSR build ----------
__global__ void k_count(const int* __restrict__ dst, int* __restrict__ counts) {
  int e = blockIdx.x * 256 + threadIdx.x;
  if (e < NE) atomicAdd(&counts[dst[e]], 1);
}

__global__ __launch_bounds__(256) void k_scan_local(const int* __restrict__ counts,
                                                    int* __restrict__ tmp,
                                                    int* __restrict__ bsums) {
  __shared__ int wsum[4];
  const int t = threadIdx.x, lane = t & 63, wid = t >> 6;
  const int base = blockIdx.x * 1024 + t * 4;
  int v[4];
  #pragma unroll
  for (int j = 0; j < 4; ++j) {
    int idx = base + j;
    v[j] = (idx < NN) ? counts[idx] : 0;
  }
  int s = v[0] + v[1] + v[2] + v[3];
  int inc = s;
  #pragma unroll
  for (int off = 1; off < 64; off <<= 1) {
    int u = __shfl_up(inc, off);
    if (lane >= off) inc += u;
  }
  if (lane == 63) wsum[wid] = inc;
  __syncthreads();
  if (t == 0) {
    int a = 0;
    #pragma unroll
    for (int j = 0; j < 4; ++j) { int xv = wsum[j]; wsum[j] = a; a += xv; }
    bsums[blockIdx.x] = a;
  }
  __syncthreads();
  int run = (inc - s) + wsum[wid];
  #pragma unroll
  for (int j = 0; j < 4; ++j) {
    int idx = base + j;
    if (idx < NN) tmp[idx] = run;
    run += v[j];
  }
}

__global__ void k_scan_top(int* __restrict__ bsums, int* __restrict__ rowptr) {
  const int lane = threadIdx.x;   // 64 threads
  int v = (lane < NB_SCAN) ? bsums[lane] : 0;
  int inc = v;
  #pragma unroll
  for (int off = 1; off < 64; off <<= 1) {
    int u = __shfl_up(inc, off);
    if (lane >= off) inc += u;
  }
  if (lane < NB_SCAN) bsums[lane] = inc - v;
  if (lane == 63) rowptr[NN] = inc;
}

__global__ __launch_bounds__(256) void k_scan_add(const int* __restrict__ tmp,
                                                  const int* __restrict__ bsums,
                                                  int* __restrict__ rowptr,
                                                  int* __restrict__ nxt) {
  const int t = threadIdx.x;
  const int base = blockIdx.x * 1024 + t * 4;
  const int off = bsums[blockIdx.x];
  #pragma unroll
  for (int j = 0; j < 4; ++j) {
    int idx = base + j;
    if (idx < NN) {
      int val = tmp[idx] + off;
      rowptr[idx] = val;
      nxt[idx] = val;
    }
  }
}

// packed CSR entry: low 32 = src index, high 32 = weight bits
__global__ void k_scatter(const int* __restrict__ src, const int* __restrict__ dst,
                          const float* __restrict__ w, int* __restrict__ nxt,
                          long long* __restrict__ csrp) {
  int e = blockIdx.x * 256 + threadIdx.x;
  if (e < NE) {
    int i = dst[e];
    int p = atomicAdd(&nxt[i], 1);
    long long pk = (long long)(unsigned int)src[e] |
                   ((long long)(unsigned int)__float_as_uint(w[e]) << 32);
    csrp[p] = pk;
  }
}

// ---------- SpMM1: 4 groups x 16 lanes, 4 edges/wave concurrent ----------
// lane = g*16 + ql; lane covers cols [8*ql, 8*ql+8) via ushort8 (16B) loads.
// group g takes edges e0+g, e0+g+4, ...; unroll-4 -> 16 gathers in flight.
// partials combined via __shfl_xor(16) + __shfl_xor(32); lanes 0..15 write row.
__global__ __launch_bounds__(256) void k_spmm1(const unsigned short* __restrict__ hb0,
                                               const int* __restrict__ rowptr,
                                               const long long* __restrict__ csrp,
                                               const float* __restrict__ b1,
                                               const float* __restrict__ mask,
                                               unsigned short* __restrict__ hb1) {
  const int t = threadIdx.x, lane = t & 63, wv = t >> 6;
  const int g = lane >> 4, ql = lane & 15;
  const int i = blockIdx.x * 4 + wv;
  const int c0 = ql * 8;
  const int e0 = rowptr[i], e1 = rowptr[i + 1];
  const int nE = e1 - e0;
  const int m = (nE + 3 - g) >> 2;             // edges handled by this group
  const long long* ep = csrp + e0 + g;

  float a0[8] = {0.f,0.f,0.f,0.f,0.f,0.f,0.f,0.f};
  float a1[8] = {0.f,0.f,0.f,0.f,0.f,0.f,0.f,0.f};
  int j = 0;
  for (; j + 3 < m; j += 4) {                  // 16 gathers in flight per wave
    long long p0 = ep[4*j], p1 = ep[4*j+4], p2 = ep[4*j+8], p3 = ep[4*j+12];
    int s0 = (int)p0, s1 = (int)p1, s2 = (int)p2, s3 = (int)p3;
    float w0 = __uint_as_float((unsigned int)((unsigned long long)p0 >> 32));
    float w1 = __uint_as_float((unsigned int)((unsigned long long)p1 >> 32));
    float w2 = __uint_as_float((unsigned int)((unsigned long long)p2 >> 32));
    float w3 = __uint_as_float((unsigned int)((unsigned long long)p3 >> 32));
    us8 h0 = *(const us8*)&hb0[s0 * HID + c0];
    us8 h1 = *(const us8*)&hb0[s1 * HID + c0];
    us8 h2 = *(const us8*)&hb0[s2 * HID + c0];
    us8 h3 = *(const us8*)&hb0[s3 * HID + c0];
    #pragma unroll
    for (int k = 0; k < 8; ++k) {
      a0[k] += w0 * bf2f(h0[k]);
      a1[k] += w1 * bf2f(h1[k]);
      a0[k] += w2 * bf2f(h2[k]);
      a1[k] += w3 * bf2f(h3[k]);
    }
  }
  for (; j < m; ++j) {
    long long p = ep[4*j];
    int s = (int)p;
    float w = __uint_as_float((unsigned int)((unsigned long long)p >> 32));
    us8 h = *(const us8*)&hb0[s * HID + c0];
    #pragma unroll
    for (int k = 0; k < 8; ++k) a0[k] += w * bf2f(h[k]);
  }
  float v[8];
  #pragma unroll
  for (int k = 0; k < 8; ++k) {
    v[k] = a0[k] + a1[k];
    v[k] += __shfl_xor(v[k], 16);
    v[k] += __shfl_xor(v[k], 32);
  }
  if (g == 0) {
    const float4 bbA = *(const float4*)&b1[c0];
    const float4 bbB = *(const float4*)&b1[c0 + 4];
    const float4 mkA = *(const float4*)&mask[(size_t)i * HID + c0];
    const float4 mkB = *(const float4*)&mask[(size_t)i * HID + c0 + 4];
    us8 o;
    o[0] = f2bf(fmaxf(v[0] + bbA.x, 0.f) * mkA.x);
    o[1] = f2bf(fmaxf(v[1] + bbA.y, 0.f) * mkA.y);
    o[2] = f2bf(fmaxf(v[2] + bbA.z, 0.f) * mkA.z);
    o[3] = f2bf(fmaxf(v[3] + bbA.w, 0.f) * mkA.w);
    o[4] = f2bf(fmaxf(v[4] + bbB.x, 0.f) * mkB.x);
    o[5] = f2bf(fmaxf(v[5] + bbB.y, 0.f) * mkB.y);
    o[6] = f2bf(fmaxf(v[6] + bbB.z, 0.f) * mkB.z);
    o[7] = f2bf(fmaxf(v[7] + bbB.w, 0.f) * mkB.w);
    *(us8*)&hb1[(size_t)i * HID + c0] = o;
  }
}

// ---------- GEMM2: h2b[NN][40] = bf16(hb1 @ W2) (bf16 MFMA, 48-col padded) ----------
#define BKP2 136
__global__ __launch_bounds__(256) void k_gemm2(const unsigned short* __restrict__ hb1,
                                               const float* __restrict__ W2,
                                               unsigned short* __restrict__ h2b) {
  __shared__ unsigned short As[64 * BKP2];
  __shared__ unsigned short Bs[48 * BKP2];
  const int t = threadIdx.x;
  const int r0 = blockIdx.x * 64;
  const int wave = t >> 6, lane = t & 63;
  const int quad = lane >> 4, mr = lane & 15;
  const int mrow0 = wave * 16;

  const int ar = t >> 2, aq = t & 3;
  int grow = r0 + ar; if (grow > NN - 1) grow = NN - 1;
  const us8* hrow = (const us8*)(hb1 + (size_t)grow * HID);
  #pragma unroll
  for (int i = 0; i < 4; ++i) {
    us8 v = hrow[aq + i * 4];
    *(us8*)&As[ar * BKP2 + aq * 8 + i * 32] = v;
  }
  if (t < 192) {
    int n = t >> 2, q = t & 3;
    #pragma unroll
    for (int kk = 0; kk < 32; ++kk) {
      int k = q * 32 + kk;
      float val = (n < NOUT) ? W2[k * NOUT + n] : 0.f;
      Bs[n * BKP2 + k] = f2bf(val);
    }
  }
  __syncthreads();

  const v4f vzero = {0.f, 0.f, 0.f, 0.f};
  v4f acc[3] = {vzero, vzero, vzero};
  #pragma unroll
  for (int ks = 0; ks < HID; ks += 32) {
    v8bf a = *(const v8bf*)&As[(mrow0 + mr) * BKP2 + ks + quad * 8];
    #pragma unroll
    for (int j = 0; j < 3; ++j) {
      v8bf b = *(const v8bf*)&Bs[(j * 16 + mr) * BKP2 + ks + quad * 8];
      acc[j] = __builtin_amdgcn_mfma_f32_16x16x32_bf16(a, b, acc[j], 0, 0, 0);
    }
  }
  #pragma unroll
  for (int j = 0; j < 3; ++j)
    #pragma unroll
    for (int rr = 0; rr < 4; ++rr) {
      int row = r0 + mrow0 + quad * 4 + rr;
      int col = j * 16 + mr;
      if (row < NN && col < NOUT) h2b[(size_t)row * NOUT + col] = f2bf(acc[j][rr]);
    }
}

// ---------- SpMM2: 4 groups x 16 lanes (10 active), 4 edges/wave ----------
// lane = g*16 + ql, active if ql<10; covers cols [4*ql, 4*ql+4) via ushort4 (8B).
__global__ __launch_bounds__(256) void k_spmm2(const unsigned short* __restrict__ h2b,
                                               const int* __restrict__ rowptr,
                                               const long long* __restrict__ csrp,
                                               const float* __restrict__ b2,
                                               float* __restrict__ out) {
  const int t = threadIdx.x, lane = t & 63;
  const int g = lane >> 4, ql = lane & 15;
  const int i = blockIdx.x * 4 + (t >> 6);
  const int act = (ql < 10);
  const int c0 = act ? ql * 4 : 0;             // clamp inactive lanes in-bounds
  const int e0 = rowptr[i], e1 = rowptr[i + 1];
  const int nE = e1 - e0;
  const int m = (nE + 3 - g) >> 2;
  const long long* ep = csrp + e0 + g;

  float a0[4] = {0.f, 0.f, 0.f, 0.f};
  float a1[4] = {0.f, 0.f, 0.f, 0.f};
  int j = 0;
  for (; j + 3 < m; j += 4) {
    long long p0 = ep[4*j], p1 = ep[4*j+4], p2 = ep[4*j+8], p3 = ep[4*j+12];
    int s0 = (int)p0, s1 = (int)p1, s2 = (int)p2, s3 = (int)p3;
    float w0 = __uint_as_float((unsigned int)((unsigned long long)p0 >> 32));
    float w1 = __uint_as_float((unsigned int)((unsigned long long)p1 >> 32));
    float w2 = __uint_as_float((unsigned int)((unsigned long long)p2 >> 32));
    float w3 = __uint_as_float((unsigned int)((unsigned long long)p3 >> 32));
    us4 h0 = *(const us4*)&h2b[s0 * NOUT + c0];
    us4 h1 = *(const us4*)&h2b[s1 * NOUT + c0];
    us4 h2 = *(const us4*)&h2b[s2 * NOUT + c0];
    us4 h3 = *(const us4*)&h2b[s3 * NOUT + c0];
    #pragma unroll
    for (int k = 0; k < 4; ++k) {
      a0[k] += w0 * bf2f(h0[k]);
      a1[k] += w1 * bf2f(h1[k]);
      a0[k] += w2 * bf2f(h2[k]);
      a1[k] += w3 * bf2f(h3[k]);
    }
  }
  for (; j < m; ++j) {
    long long p = ep[4*j];
    int s = (int)p;
    float w = __uint_as_float((unsigned int)((unsigned long long)p >> 32));
    us4 h = *(const us4*)&h2b[s * NOUT + c0];
    #pragma unroll
    for (int k = 0; k < 4; ++k) a0[k] += w * bf2f(h[k]);
  }
  float v[4];
  #pragma unroll
  for (int k = 0; k < 4; ++k) {
    v[k] = a0[k] + a1[k];
    v[k] += __shfl_xor(v[k], 16);
    v[k] += __shfl_xor(v[k], 32);
  }
  if (g == 0 && act) {
    const float4 bb = *(const float4*)&b2[c0];
    float4 o;
    o.x = v[0] + bb.x;
    o.y = v[1] + bb.y;
    o.z = v[2] + bb.z;
    o.w = v[3] + bb.w;
    *(float4*)&out[(size_t)i * NOUT + c0] = o;
  }
}

extern "C" void kernel_launch(void* const* d_in, const int* in_sizes, int n_in,
                              void* d_out, int out_size, void* d_ws, size_t ws_size,
                              hipStream_t stream) {
  const float* x   = (const float*)d_in[0];
  const float* W1  = (const float*)d_in[1];
  const float* b1  = (const float*)d_in[2];
  const float* W2  = (const float*)d_in[3];
  const float* b2  = (const float*)d_in[4];
  const float* ew  = (const float*)d_in[5];
  const float* msk = (const float*)d_in[6];
  const int* esrc  = (const int*)d_in[7];
  const int* edst  = (const int*)d_in[8];
  float* out = (float*)d_out;

  char* ws = (char*)d_ws;
  unsigned short* hb0 = (unsigned short*)ws; ws += (size_t)NN * HID * 2;   // 12.8 MB
  unsigned short* hb1 = (unsigned short*)ws; ws += (size_t)NN * HID * 2;   // 12.8 MB
  unsigned short* h2b = (unsigned short*)ws; ws += (size_t)NN * NOUT * 2;  // 4 MB
  unsigned short* W1t = (unsigned short*)ws; ws += (size_t)HID * FIN * 2;  // 128 KB
  long long* csrp     = (long long*)ws;      ws += (size_t)NE * 8;         // 6.4 MB
  int* counts         = (int*)ws;            ws += (size_t)NN * 4;
  int* tmp            = (int*)ws;            ws += (size_t)NN * 4;
  int* rowptr         = (int*)ws;            ws += (size_t)(NN + 16) * 4;
  int* nxt            = (int*)ws;            ws += (size_t)NN * 4;
  int* bsums          = (int*)ws;            ws += (size_t)64 * 4;

  k_w1t       <<<(FIN * HID) / 256, 256, 0, stream>>>(W1, W1t, counts);
  k_gemm1     <<<(NN + BM1 - 1) / BM1, 256, 0, stream>>>(x, W1t, hb0);
  k_count     <<<(NE + 255) / 256, 256, 0, stream>>>(edst, counts);
  k_scan_local<<<NB_SCAN, 256, 0, stream>>>(counts, tmp, bsums);
  k_scan_top  <<<1, 64, 0, stream>>>(bsums, rowptr);
  k_scan_add  <<<NB_SCAN, 256, 0, stream>>>(tmp, bsums, rowptr, nxt);
  k_scatter   <<<(NE + 255) / 256, 256, 0, stream>>>(esrc, edst, ew, nxt, csrp);
  k_spmm1     <<<NN / 4, 256, 0, stream>>>(hb0, rowptr, csrp, b1, msk, hb1);
  k_gemm2     <<<(NN + 63) / 64, 256, 0, stream>>>(hb1, W2, h2b);
  k_spmm2     <<<(NN + 3) / 4, 256, 0, stream>>>(h2b, rowptr, csrp, b2, out);
}